// Round 1
// baseline (480.954 us; speedup 1.0000x reference)
//
#include <hip/hip_runtime.h>

#define N_NODES 50000
#define N_EDGES 800000
#define F_IN    256
#define C_DIM   64
#define H_HEADS 2
#define HC      128   // H*C

// ---------------- workspace layout (bytes) ----------------
// h   : N*128 f32 = 25,600,000   (reused later for uv)
// h2  : N*128 f32 = 25,600,000
// a_s : N*2  f32  =    400,000
// a_d : N*2  f32  =    400,000
// offs: (N+1) i32 =    200,064 (padded)
// deg : N i32     =    200,000
// cur : N i32     =    200,000
// part: 256 i32   =      1,024
// csr : E i32     =  3,200,000
static constexpr size_t OFF_H    = 0;
static constexpr size_t OFF_H2   = 25600000;
static constexpr size_t OFF_AS   = OFF_H2  + 25600000;   // 51,200,000
static constexpr size_t OFF_AD   = OFF_AS  + 400000;
static constexpr size_t OFF_OFFS = OFF_AD  + 400000;
static constexpr size_t OFF_DEG  = OFF_OFFS + 200064;
static constexpr size_t OFF_CUR  = OFF_DEG + 200000;
static constexpr size_t OFF_PART = OFF_CUR + 200000;
static constexpr size_t OFF_CSR  = OFF_PART + 1024;

// ---------------- k1: h = x @ W  [50000,256]@[256,128] ----------------
__global__ __launch_bounds__(256) void k_gemm_xw(const float* __restrict__ x,
                                                 const float* __restrict__ W,
                                                 float* __restrict__ h) {
    __shared__ float xs[16][F_IN];
    const int rb = blockIdx.x * 16;
    const int t  = threadIdx.x;
    // stage 16 rows of x (16*256 f32 = 1024 float4)
    const float4* xv = (const float4*)(x + (size_t)rb * F_IN);
    float4* xsv = (float4*)&xs[0][0];
#pragma unroll
    for (int i = 0; i < 4; ++i) xsv[t + 256 * i] = xv[t + 256 * i];
    __syncthreads();

    const int j  = t & 127;
    const int r2 = t >> 7;           // 0/1; rows r2, r2+2, ..., r2+14
    const float* Wc = W + j;
    float acc[8] = {};
    for (int k = 0; k < F_IN; k += 4) {
        float w0 = Wc[(k + 0) * HC];
        float w1 = Wc[(k + 1) * HC];
        float w2 = Wc[(k + 2) * HC];
        float w3 = Wc[(k + 3) * HC];
#pragma unroll
        for (int i = 0; i < 8; ++i) {
            float4 xq = *(const float4*)&xs[r2 + 2 * i][k];
            acc[i] += xq.x * w0 + xq.y * w1 + xq.z * w2 + xq.w * w3;
        }
    }
#pragma unroll
    for (int i = 0; i < 8; ++i)
        h[(size_t)(rb + r2 + 2 * i) * HC + j] = acc[i];
}

// ---------------- k2: per-(node,head) attention logits ----------------
__global__ __launch_bounds__(256) void k_att(const float* __restrict__ h,
                                             const float* __restrict__ att_src,
                                             const float* __restrict__ att_dst,
                                             float* __restrict__ as_,
                                             float* __restrict__ ad_) {
    int id = blockIdx.x * 256 + threadIdx.x;
    if (id >= N_NODES * H_HEADS) return;
    int n = id >> 1, hd = id & 1;
    const float4* hv = (const float4*)(h + (size_t)n * HC + hd * C_DIM);
    const float4* sv = (const float4*)(att_src + hd * C_DIM);
    const float4* dv = (const float4*)(att_dst + hd * C_DIM);
    float as = 0.f, ad = 0.f;
#pragma unroll
    for (int q = 0; q < 16; ++q) {
        float4 hh = hv[q], ss = sv[q], dd = dv[q];
        as += hh.x * ss.x + hh.y * ss.y + hh.z * ss.z + hh.w * ss.w;
        ad += hh.x * dd.x + hh.y * dd.y + hh.z * dd.z + hh.w * dd.w;
    }
    as_[id] = as;
    ad_[id] = ad;
}

// ---------------- CSR build ----------------
__global__ void k_hist(const int* __restrict__ dst, int* __restrict__ deg) {
    int e = blockIdx.x * 256 + threadIdx.x;   // grid exact: 3125*256 = 800000
    atomicAdd(&deg[dst[e]], 1);
}

__global__ void k_scan_part(const int* __restrict__ deg, int* __restrict__ part) {
    __shared__ int sd[256];
    int i = blockIdx.x * 256 + threadIdx.x;
    sd[threadIdx.x] = (i < N_NODES) ? deg[i] : 0;
    __syncthreads();
    for (int off = 128; off > 0; off >>= 1) {
        if (threadIdx.x < off) sd[threadIdx.x] += sd[threadIdx.x + off];
        __syncthreads();
    }
    if (threadIdx.x == 0) part[blockIdx.x] = sd[0];
}

__global__ void k_scan_mid(int* __restrict__ part, int* __restrict__ offs, int nb) {
    __shared__ int sd[256];
    int t = threadIdx.x;
    int v = (t < nb) ? part[t] : 0;
    sd[t] = v;
    __syncthreads();
    for (int off = 1; off < 256; off <<= 1) {
        int u = (t >= off) ? sd[t - off] : 0;
        __syncthreads();
        sd[t] += u;
        __syncthreads();
    }
    if (t < nb) part[t] = sd[t] - v;       // exclusive block offsets
    if (t == 255) offs[N_NODES] = sd[255]; // total = E
}

__global__ void k_scan_final(const int* __restrict__ deg, const int* __restrict__ part,
                             int* __restrict__ offs) {
    __shared__ int sd[256];
    int t = threadIdx.x;
    int i = blockIdx.x * 256 + t;
    int v = (i < N_NODES) ? deg[i] : 0;
    sd[t] = v;
    __syncthreads();
    for (int off = 1; off < 256; off <<= 1) {
        int u = (t >= off) ? sd[t - off] : 0;
        __syncthreads();
        sd[t] += u;
        __syncthreads();
    }
    if (i < N_NODES) offs[i] = part[blockIdx.x] + sd[t] - v;
}

__global__ void k_scatter(const int* __restrict__ src, const int* __restrict__ dst,
                          int* __restrict__ cur, int* __restrict__ csr_src) {
    int e = blockIdx.x * 256 + threadIdx.x;
    int d = dst[e];
    int pos = atomicAdd(&cur[d], 1);
    csr_src[pos] = src[e];
}

// ---------------- k6: per-node softmax + aggregate + bias + lrelu ----------------
__global__ __launch_bounds__(128) void k_agg(const float* __restrict__ h,
                                             const float* __restrict__ as_,
                                             const float* __restrict__ ad_,
                                             const int* __restrict__ offs,
                                             const int* __restrict__ csr_src,
                                             const float* __restrict__ conv_bias,
                                             float* __restrict__ h2) {
    const int n  = blockIdx.x;
    const int c  = threadIdx.x;
    const int hd = c >> 6;
    const float adn = ad_[n * 2 + hd];
    float acc = 0.f, accw = 0.f;
    const int beg = offs[n], end = offs[n + 1];
    for (int i = beg; i < end; ++i) {
        int s = csr_src[i];
        float e = as_[s * 2 + hd] + adn;
        e = fmaxf(e, 0.2f * e);          // leaky_relu(0.2)
        float w = __expf(e);             // no max-shift: |e| <~ 12, safe in fp32
        accw += w;
        acc  += w * h[(size_t)s * HC + c];
    }
    { // PyG self-loop
        float e = as_[n * 2 + hd] + adn;
        e = fmaxf(e, 0.2f * e);
        float w = __expf(e);
        accw += w;
        acc  += w * h[(size_t)n * HC + c];
    }
    float o = acc / accw + conv_bias[c];
    h2[(size_t)n * HC + c] = fmaxf(o, 0.01f * o);   // leaky_relu(0.01)
}

// ---------------- k7: uv[n] = [h2[n]@fc1_top | h2[n]@fc1_bot] ----------------
__global__ __launch_bounds__(256) void k_gemm_uv(const float* __restrict__ h2,
                                                 const float* __restrict__ fc1,
                                                 float* __restrict__ uv) {
    __shared__ float hs[16][HC];
    const int rb = blockIdx.x * 16;
    const int t  = threadIdx.x;
    const float4* hv = (const float4*)(h2 + (size_t)rb * HC);
    float4* hsv = (float4*)&hs[0][0];
#pragma unroll
    for (int i = 0; i < 2; ++i) hsv[t + 256 * i] = hv[t + 256 * i];
    __syncthreads();

    const int j  = t & 127;
    const int r2 = t >> 7;
    const float* wc = (j < C_DIM) ? (fc1 + j) : (fc1 + 128 * C_DIM + (j - C_DIM));
    float acc[8] = {};
    for (int k = 0; k < HC; k += 4) {
        float w0 = wc[(k + 0) * C_DIM];
        float w1 = wc[(k + 1) * C_DIM];
        float w2 = wc[(k + 2) * C_DIM];
        float w3 = wc[(k + 3) * C_DIM];
#pragma unroll
        for (int i = 0; i < 8; ++i) {
            float4 xq = *(const float4*)&hs[r2 + 2 * i][k];
            acc[i] += xq.x * w0 + xq.y * w1 + xq.z * w2 + xq.w * w3;
        }
    }
#pragma unroll
    for (int i = 0; i < 8; ++i)
        uv[(size_t)(rb + r2 + 2 * i) * HC + j] = acc[i];
}

// ---------------- k8: per-edge MLP tail (BN + lrelu + fc2) ----------------
__global__ __launch_bounds__(256) void k_edge(const int* __restrict__ src,
                                              const int* __restrict__ dst,
                                              const float* __restrict__ uv,
                                              const float* __restrict__ fc1_b,
                                              const float* __restrict__ gamma,
                                              const float* __restrict__ beta,
                                              const float* __restrict__ mean,
                                              const float* __restrict__ var,
                                              const float* __restrict__ fc2_w,
                                              const float* __restrict__ fc2_b,
                                              float* __restrict__ out) {
    const int t    = threadIdx.x;
    const int e    = blockIdx.x * 4 + (t >> 6);   // grid exact: 200000*4 = 800000
    const int lane = t & 63;
    const int s = src[e], d = dst[e];
    float y = uv[(size_t)s * HC + lane] + uv[(size_t)d * HC + 64 + lane] + fc1_b[lane];
    float scale = gamma[lane] * rsqrtf(var[lane] + 1e-5f);
    y = (y - mean[lane]) * scale + beta[lane];
    y = fmaxf(y, 0.01f * y);
    float p0 = y * fc2_w[lane * 3 + 0];
    float p1 = y * fc2_w[lane * 3 + 1];
    float p2 = y * fc2_w[lane * 3 + 2];
#pragma unroll
    for (int off = 32; off > 0; off >>= 1) {
        p0 += __shfl_down(p0, off, 64);
        p1 += __shfl_down(p1, off, 64);
        p2 += __shfl_down(p2, off, 64);
    }
    if (lane == 0) {
        out[(size_t)e * 3 + 0] = p0 + fc2_b[0];
        out[(size_t)e * 3 + 1] = p1 + fc2_b[1];
        out[(size_t)e * 3 + 2] = p2 + fc2_b[2];
    }
}

extern "C" void kernel_launch(void* const* d_in, const int* in_sizes, int n_in,
                              void* d_out, int out_size, void* d_ws, size_t ws_size,
                              hipStream_t stream) {
    const float* x        = (const float*)d_in[0];
    const int*   ei       = (const int*)d_in[1];
    const float* W        = (const float*)d_in[2];
    const float* att_src  = (const float*)d_in[3];
    const float* att_dst  = (const float*)d_in[4];
    const float* conv_b   = (const float*)d_in[5];
    const float* fc1_w    = (const float*)d_in[6];
    const float* fc1_b    = (const float*)d_in[7];
    const float* gamma    = (const float*)d_in[8];
    const float* beta     = (const float*)d_in[9];
    const float* mean     = (const float*)d_in[10];
    const float* var      = (const float*)d_in[11];
    const float* fc2_w    = (const float*)d_in[12];
    const float* fc2_b    = (const float*)d_in[13];
    float*       out      = (float*)d_out;
    char*        ws       = (char*)d_ws;

    const int* src = ei;             // edge_index[0]
    const int* dst = ei + N_EDGES;   // edge_index[1]

    float* h   = (float*)(ws + OFF_H);
    float* h2  = (float*)(ws + OFF_H2);
    float* uv  = (float*)(ws + OFF_H);   // reuse: h dead after k_agg
    float* as_ = (float*)(ws + OFF_AS);
    float* ad_ = (float*)(ws + OFF_AD);
    int*   offs= (int*)(ws + OFF_OFFS);
    int*   deg = (int*)(ws + OFF_DEG);
    int*   cur = (int*)(ws + OFF_CUR);
    int*   part= (int*)(ws + OFF_PART);
    int*   csr = (int*)(ws + OFF_CSR);

    // CSR build (independent of GEMMs)
    hipMemsetAsync(deg, 0, N_NODES * sizeof(int), stream);
    k_hist      <<<N_EDGES / 256, 256, 0, stream>>>(dst, deg);
    k_scan_part <<<(N_NODES + 255) / 256, 256, 0, stream>>>(deg, part);
    k_scan_mid  <<<1, 256, 0, stream>>>(part, offs, (N_NODES + 255) / 256);
    k_scan_final<<<(N_NODES + 255) / 256, 256, 0, stream>>>(deg, part, offs);
    hipMemcpyAsync(cur, offs, N_NODES * sizeof(int), hipMemcpyDeviceToDevice, stream);
    k_scatter   <<<N_EDGES / 256, 256, 0, stream>>>(src, dst, cur, csr);

    // node pipeline
    k_gemm_xw<<<N_NODES / 16, 256, 0, stream>>>(x, W, h);
    k_att    <<<(N_NODES * H_HEADS + 255) / 256, 256, 0, stream>>>(h, att_src, att_dst, as_, ad_);
    k_agg    <<<N_NODES, 128, 0, stream>>>(h, as_, ad_, offs, csr, conv_b, h2);
    k_gemm_uv<<<N_NODES / 16, 256, 0, stream>>>(h2, fc1_w, uv);

    // edge tail
    k_edge<<<N_EDGES / 4, 256, 0, stream>>>(src, dst, uv, fc1_b, gamma, beta, mean, var,
                                            fc2_w, fc2_b, out);
}

// Round 2
// 323.925 us; speedup vs baseline: 1.4848x; 1.4848x over previous
//
#include <hip/hip_runtime.h>

#define N_NODES 50000
#define N_EDGES 800000
#define F_IN    256
#define C_DIM   64
#define H_HEADS 2
#define HC      128   // H*C

// ---------------- workspace layout (bytes) ----------------
static constexpr size_t OFF_HBF  = 0;                        // bf16 h   [N][128] = 12.8 MB
static constexpr size_t OFF_H2   = 12800000;                 // f32 h2   [N][128] = 25.6 MB
static constexpr size_t OFF_AB   = OFF_H2 + 25600000;        // bf16 A|B [N][128] = 12.8 MB
static constexpr size_t OFF_AS   = OFF_AB + 12800000;
static constexpr size_t OFF_AD   = OFF_AS + 400000;
static constexpr size_t OFF_OFFS = OFF_AD + 400000;
static constexpr size_t OFF_DEG  = OFF_OFFS + 200064;
static constexpr size_t OFF_CUR  = OFF_DEG + 200000;
static constexpr size_t OFF_PART = OFF_CUR + 200000;
static constexpr size_t OFF_CSR  = OFF_PART + 1024;

__device__ __forceinline__ float2 bf2(unsigned u) {
    float2 r;
    r.x = __uint_as_float(u << 16);
    r.y = __uint_as_float(u & 0xffff0000u);
    return r;
}
__device__ __forceinline__ unsigned short f2bf(float f) {
    unsigned u = __float_as_uint(f);
    return (unsigned short)((u + 0x7fffu + ((u >> 16) & 1u)) >> 16);  // RNE
}

// ---------------- k1: h_bf = bf16(x @ W) ----------------
__global__ __launch_bounds__(256) void k_gemm_xw(const float* __restrict__ x,
                                                 const float* __restrict__ W,
                                                 unsigned short* __restrict__ h_bf) {
    __shared__ float xs[16][F_IN];
    const int rb = blockIdx.x * 16;
    const int t  = threadIdx.x;
    const float4* xv = (const float4*)(x + (size_t)rb * F_IN);
    float4* xsv = (float4*)&xs[0][0];
#pragma unroll
    for (int i = 0; i < 4; ++i) xsv[t + 256 * i] = xv[t + 256 * i];
    __syncthreads();

    const int j  = t & 127;
    const int r2 = t >> 7;
    const float* Wc = W + j;
    float acc[8] = {};
    for (int k = 0; k < F_IN; k += 4) {
        float w0 = Wc[(k + 0) * HC];
        float w1 = Wc[(k + 1) * HC];
        float w2 = Wc[(k + 2) * HC];
        float w3 = Wc[(k + 3) * HC];
#pragma unroll
        for (int i = 0; i < 8; ++i) {
            float4 xq = *(const float4*)&xs[r2 + 2 * i][k];
            acc[i] += xq.x * w0 + xq.y * w1 + xq.z * w2 + xq.w * w3;
        }
    }
#pragma unroll
    for (int i = 0; i < 8; ++i)
        h_bf[(size_t)(rb + r2 + 2 * i) * HC + j] = f2bf(acc[i]);
}

// ---------------- k2: attention logits from bf16 h ----------------
__global__ __launch_bounds__(256) void k_att(const unsigned short* __restrict__ h_bf,
                                             const float* __restrict__ att_src,
                                             const float* __restrict__ att_dst,
                                             float* __restrict__ as_,
                                             float* __restrict__ ad_) {
    __shared__ float sa[HC], sd[HC];
    int t = threadIdx.x;
    if (t < HC) { sa[t] = att_src[t]; sd[t] = att_dst[t]; }
    __syncthreads();
    int n = blockIdx.x * 256 + t;
    if (n >= N_NODES) return;
    const uint2* hv = (const uint2*)(h_bf + (size_t)n * HC);
    float as0 = 0, as1 = 0, ad0 = 0, ad1 = 0;
#pragma unroll
    for (int q = 0; q < 16; ++q) {
        uint2 u = hv[q];
        float2 fa = bf2(u.x), fb = bf2(u.y);
        int c = 4 * q;
        as0 += fa.x * sa[c] + fa.y * sa[c + 1] + fb.x * sa[c + 2] + fb.y * sa[c + 3];
        ad0 += fa.x * sd[c] + fa.y * sd[c + 1] + fb.x * sd[c + 2] + fb.y * sd[c + 3];
    }
#pragma unroll
    for (int q = 16; q < 32; ++q) {
        uint2 u = hv[q];
        float2 fa = bf2(u.x), fb = bf2(u.y);
        int c = 4 * q;
        as1 += fa.x * sa[c] + fa.y * sa[c + 1] + fb.x * sa[c + 2] + fb.y * sa[c + 3];
        ad1 += fa.x * sd[c] + fa.y * sd[c + 1] + fb.x * sd[c + 2] + fb.y * sd[c + 3];
    }
    as_[n * 2] = as0; as_[n * 2 + 1] = as1;
    ad_[n * 2] = ad0; ad_[n * 2 + 1] = ad1;
}

// ---------------- CSR build ----------------
__global__ void k_hist(const int* __restrict__ dst, int* __restrict__ deg) {
    int e = blockIdx.x * 256 + threadIdx.x;
    atomicAdd(&deg[dst[e]], 1);
}

__global__ void k_scan_part(const int* __restrict__ deg, int* __restrict__ part) {
    __shared__ int sd[256];
    int i = blockIdx.x * 256 + threadIdx.x;
    sd[threadIdx.x] = (i < N_NODES) ? deg[i] : 0;
    __syncthreads();
    for (int off = 128; off > 0; off >>= 1) {
        if (threadIdx.x < off) sd[threadIdx.x] += sd[threadIdx.x + off];
        __syncthreads();
    }
    if (threadIdx.x == 0) part[blockIdx.x] = sd[0];
}

__global__ void k_scan_mid(int* __restrict__ part, int* __restrict__ offs, int nb) {
    __shared__ int sd[256];
    int t = threadIdx.x;
    int v = (t < nb) ? part[t] : 0;
    sd[t] = v;
    __syncthreads();
    for (int off = 1; off < 256; off <<= 1) {
        int u = (t >= off) ? sd[t - off] : 0;
        __syncthreads();
        sd[t] += u;
        __syncthreads();
    }
    if (t < nb) part[t] = sd[t] - v;
    if (t == 255) offs[N_NODES] = sd[255];
}

__global__ void k_scan_final(const int* __restrict__ deg, const int* __restrict__ part,
                             int* __restrict__ offs, int* __restrict__ cur) {
    __shared__ int sd[256];
    int t = threadIdx.x;
    int i = blockIdx.x * 256 + t;
    int v = (i < N_NODES) ? deg[i] : 0;
    sd[t] = v;
    __syncthreads();
    for (int off = 1; off < 256; off <<= 1) {
        int u = (t >= off) ? sd[t - off] : 0;
        __syncthreads();
        sd[t] += u;
        __syncthreads();
    }
    if (i < N_NODES) {
        int o = part[blockIdx.x] + sd[t] - v;
        offs[i] = o;
        cur[i]  = o;
    }
}

__global__ void k_scatter(const int* __restrict__ src, const int* __restrict__ dst,
                          int* __restrict__ cur, int* __restrict__ csr_src) {
    int e = blockIdx.x * 256 + threadIdx.x;
    int d = dst[e];
    int pos = atomicAdd(&cur[d], 1);
    csr_src[pos] = src[e];
}

// ---------------- k6: wave-per-node softmax + aggregate (bf16 gather) ----------------
__global__ __launch_bounds__(256) void k_agg(const unsigned short* __restrict__ h_bf,
                                             const float* __restrict__ as_,
                                             const float* __restrict__ ad_,
                                             const int* __restrict__ offs,
                                             const int* __restrict__ csr_src,
                                             const float* __restrict__ conv_bias,
                                             float* __restrict__ h2) {
    const int n    = blockIdx.x * 4 + (threadIdx.x >> 6);   // 12500 blocks exact
    const int lane = threadIdx.x & 63;
    const int hd   = lane >> 5;                             // channels 2*lane, 2*lane+1
    const float adn = ad_[n * 2 + hd];
    const unsigned* hrow = (const unsigned*)h_bf;
    float acc0 = 0.f, acc1 = 0.f, accw = 0.f;
    const int beg = offs[n], end = offs[n + 1];
    int i = beg;
    for (; i + 1 < end; i += 2) {
        int s0 = csr_src[i], s1 = csr_src[i + 1];
        float e0 = as_[s0 * 2 + hd] + adn;
        float e1 = as_[s1 * 2 + hd] + adn;
        unsigned u0 = hrow[(size_t)s0 * 64 + lane];
        unsigned u1 = hrow[(size_t)s1 * 64 + lane];
        e0 = fmaxf(e0, 0.2f * e0);
        e1 = fmaxf(e1, 0.2f * e1);
        float w0 = __expf(e0), w1 = __expf(e1);
        float2 f0 = bf2(u0), f1 = bf2(u1);
        acc0 += w0 * f0.x + w1 * f1.x;
        acc1 += w0 * f0.y + w1 * f1.y;
        accw += w0 + w1;
    }
    if (i < end) {
        int s0 = csr_src[i];
        float e0 = as_[s0 * 2 + hd] + adn;
        unsigned u0 = hrow[(size_t)s0 * 64 + lane];
        e0 = fmaxf(e0, 0.2f * e0);
        float w0 = __expf(e0);
        float2 f0 = bf2(u0);
        acc0 += w0 * f0.x; acc1 += w0 * f0.y; accw += w0;
    }
    {   // PyG self-loop
        float es = as_[n * 2 + hd] + adn;
        es = fmaxf(es, 0.2f * es);
        float wsl = __expf(es);
        unsigned un = hrow[(size_t)n * 64 + lane];
        float2 fn = bf2(un);
        acc0 += wsl * fn.x; acc1 += wsl * fn.y; accw += wsl;
    }
    float2 bias = ((const float2*)conv_bias)[lane];
    float o0 = acc0 / accw + bias.x;
    float o1 = acc1 / accw + bias.y;
    o0 = fmaxf(o0, 0.01f * o0);
    o1 = fmaxf(o1, 0.01f * o1);
    ((float2*)(h2 + (size_t)n * HC))[lane] = make_float2(o0, o1);
}

// ---------------- k7: AB table = bf16([u*scale | v*scale+cc]) ----------------
__global__ __launch_bounds__(256) void k_gemm_uv(const float* __restrict__ h2,
                                                 const float* __restrict__ fc1,
                                                 const float* __restrict__ fc1_b,
                                                 const float* __restrict__ gamma,
                                                 const float* __restrict__ beta,
                                                 const float* __restrict__ mean,
                                                 const float* __restrict__ var,
                                                 unsigned short* __restrict__ ab) {
    __shared__ float hs[16][HC];
    const int rb = blockIdx.x * 16;
    const int t  = threadIdx.x;
    const float4* hv = (const float4*)(h2 + (size_t)rb * HC);
    float4* hsv = (float4*)&hs[0][0];
#pragma unroll
    for (int i = 0; i < 2; ++i) hsv[t + 256 * i] = hv[t + 256 * i];
    __syncthreads();

    const int j  = t & 127;
    const int r2 = t >> 7;
    const int jj = j & 63;
    const float scale = gamma[jj] * rsqrtf(var[jj] + 1e-5f);
    const float cc = (j < C_DIM) ? 0.f : (fc1_b[jj] - mean[jj]) * scale + beta[jj];
    const float* wc = (j < C_DIM) ? (fc1 + j) : (fc1 + 128 * C_DIM + jj);
    float acc[8] = {};
    for (int k = 0; k < HC; k += 4) {
        float w0 = wc[(k + 0) * C_DIM];
        float w1 = wc[(k + 1) * C_DIM];
        float w2 = wc[(k + 2) * C_DIM];
        float w3 = wc[(k + 3) * C_DIM];
#pragma unroll
        for (int i = 0; i < 8; ++i) {
            float4 xq = *(const float4*)&hs[r2 + 2 * i][k];
            acc[i] += xq.x * w0 + xq.y * w1 + xq.z * w2 + xq.w * w3;
        }
    }
#pragma unroll
    for (int i = 0; i < 8; ++i)
        ab[(size_t)(rb + r2 + 2 * i) * HC + j] = f2bf(acc[i] * scale + cc);
}

// ---------------- k8: per-edge tail, 16 lanes/edge ----------------
__global__ __launch_bounds__(256) void k_edge(const int* __restrict__ src,
                                              const int* __restrict__ dst,
                                              const unsigned short* __restrict__ ab,
                                              const float* __restrict__ fc2_w,
                                              const float* __restrict__ fc2_b,
                                              float* __restrict__ out) {
    const int t = threadIdx.x;
    const int g = t >> 4;     // group 0..15 within block
    const int k = t & 15;     // lane within group; channels 4k..4k+3
    float wr0[4], wr1[4], wr2[4];
#pragma unroll
    for (int q = 0; q < 4; ++q) {
        int c = k * 4 + q;
        wr0[q] = fc2_w[c * 3 + 0];
        wr1[q] = fc2_w[c * 3 + 1];
        wr2[q] = fc2_w[c * 3 + 2];
    }
    const float ob0 = fc2_b[0], ob1 = fc2_b[1], ob2 = fc2_b[2];
    const int ebase = blockIdx.x * 256;   // grid 3125: 3125*256 = 800000
#pragma unroll 1
    for (int it = 0; it < 16; ++it) {
        const int e = ebase + it * 16 + g;
        const int s = src[e], d = dst[e];
        uint2 ua = *(const uint2*)(ab + (size_t)s * HC + k * 4);
        uint2 ub = *(const uint2*)(ab + (size_t)d * HC + C_DIM + k * 4);
        float2 a0 = bf2(ua.x), a1 = bf2(ua.y);
        float2 b0 = bf2(ub.x), b1 = bf2(ub.y);
        float z0 = a0.x + b0.x, z1 = a0.y + b0.y, z2 = a1.x + b1.x, z3 = a1.y + b1.y;
        z0 = fmaxf(z0, 0.01f * z0);
        z1 = fmaxf(z1, 0.01f * z1);
        z2 = fmaxf(z2, 0.01f * z2);
        z3 = fmaxf(z3, 0.01f * z3);
        float p0 = z0 * wr0[0] + z1 * wr0[1] + z2 * wr0[2] + z3 * wr0[3];
        float p1 = z0 * wr1[0] + z1 * wr1[1] + z2 * wr1[2] + z3 * wr1[3];
        float p2 = z0 * wr2[0] + z1 * wr2[1] + z2 * wr2[2] + z3 * wr2[3];
#pragma unroll
        for (int m = 1; m < 16; m <<= 1) {
            p0 += __shfl_xor(p0, m, 64);
            p1 += __shfl_xor(p1, m, 64);
            p2 += __shfl_xor(p2, m, 64);
        }
        if (k == 0) {
            float* o = out + (size_t)e * 3;
            o[0] = p0 + ob0;
            o[1] = p1 + ob1;
            o[2] = p2 + ob2;
        }
    }
}

extern "C" void kernel_launch(void* const* d_in, const int* in_sizes, int n_in,
                              void* d_out, int out_size, void* d_ws, size_t ws_size,
                              hipStream_t stream) {
    const float* x        = (const float*)d_in[0];
    const int*   ei       = (const int*)d_in[1];
    const float* W        = (const float*)d_in[2];
    const float* att_src  = (const float*)d_in[3];
    const float* att_dst  = (const float*)d_in[4];
    const float* conv_b   = (const float*)d_in[5];
    const float* fc1_w    = (const float*)d_in[6];
    const float* fc1_b    = (const float*)d_in[7];
    const float* gamma    = (const float*)d_in[8];
    const float* beta     = (const float*)d_in[9];
    const float* mean     = (const float*)d_in[10];
    const float* var      = (const float*)d_in[11];
    const float* fc2_w    = (const float*)d_in[12];
    const float* fc2_b    = (const float*)d_in[13];
    float*       out      = (float*)d_out;
    char*        ws       = (char*)d_ws;

    const int* src = ei;
    const int* dst = ei + N_EDGES;

    unsigned short* h_bf = (unsigned short*)(ws + OFF_HBF);
    float*          h2   = (float*)(ws + OFF_H2);
    unsigned short* abt  = (unsigned short*)(ws + OFF_AB);
    float*          as_  = (float*)(ws + OFF_AS);
    float*          ad_  = (float*)(ws + OFF_AD);
    int*            offs = (int*)(ws + OFF_OFFS);
    int*            deg  = (int*)(ws + OFF_DEG);
    int*            cur  = (int*)(ws + OFF_CUR);
    int*            part = (int*)(ws + OFF_PART);
    int*            csr  = (int*)(ws + OFF_CSR);

    // CSR build
    hipMemsetAsync(deg, 0, N_NODES * sizeof(int), stream);
    k_hist      <<<N_EDGES / 256, 256, 0, stream>>>(dst, deg);
    k_scan_part <<<(N_NODES + 255) / 256, 256, 0, stream>>>(deg, part);
    k_scan_mid  <<<1, 256, 0, stream>>>(part, offs, (N_NODES + 255) / 256);
    k_scan_final<<<(N_NODES + 255) / 256, 256, 0, stream>>>(deg, part, offs, cur);
    k_scatter   <<<N_EDGES / 256, 256, 0, stream>>>(src, dst, cur, csr);

    // node pipeline
    k_gemm_xw<<<N_NODES / 16, 256, 0, stream>>>(x, W, h_bf);
    k_att    <<<(N_NODES + 255) / 256, 256, 0, stream>>>(h_bf, att_src, att_dst, as_, ad_);
    k_agg    <<<N_NODES / 4, 256, 0, stream>>>(h_bf, as_, ad_, offs, csr, conv_b, h2);
    k_gemm_uv<<<N_NODES / 16, 256, 0, stream>>>(h2, fc1_w, fc1_b, gamma, beta, mean, var, abt);

    // edge tail
    k_edge<<<N_EDGES / 256, 256, 0, stream>>>(src, dst, abt, fc2_w, fc2_b, out);
}

// Round 3
// 251.912 us; speedup vs baseline: 1.9092x; 1.2859x over previous
//
#include <hip/hip_runtime.h>

#define N_NODES 50000
#define N_EDGES 800000
#define F_IN    256
#define C_DIM   64
#define HC      128   // H*C

typedef __attribute__((ext_vector_type(8))) short bf16x8;
typedef __attribute__((ext_vector_type(4))) float f32x4;

// ---------------- workspace layout (bytes) ----------------
static constexpr size_t OFF_HBF   = 0;           // u32  h packed  [N][64] = 12.8 MB
static constexpr size_t OFF_H2    = 12800000;    // u32  h2 packed [N][64] = 12.8 MB
static constexpr size_t OFF_AB    = 25600000;    // u32  ab packed [N][64] = 12.8 MB
static constexpr size_t OFF_AS    = 38400000;    // f32 [N][2]
static constexpr size_t OFF_AD    = 38800000;
static constexpr size_t OFF_OFFS  = 39200000;    // i32 N+1
static constexpr size_t OFF_DEG   = 39400064;
static constexpr size_t OFF_CUR   = 39600064;
static constexpr size_t OFF_PART  = 39800064;
static constexpr size_t OFF_CSR   = 39801088;    // i32 E
static constexpr size_t OFF_WT    = 43001088;    // bf16 Wt   [128][256] = 64 KB
static constexpr size_t OFF_FC1T  = 43066624;    // bf16 fc1t [128][128] = 32 KB
static constexpr size_t OFF_SCALE = 43099392;    // f32 [128]
static constexpr size_t OFF_CC    = 43099904;    // f32 [128]

__device__ __forceinline__ float2 bf2(unsigned u) {
    float2 r;
    r.x = __uint_as_float(u << 16);
    r.y = __uint_as_float(u & 0xffff0000u);
    return r;
}
__device__ __forceinline__ unsigned short f2bf(float f) {
    unsigned u = __float_as_uint(f);
    return (unsigned short)((u + 0x7fffu + ((u >> 16) & 1u)) >> 16);  // RNE
}
// packed-channel mapping: word L (0..63) holds channels (c0(L), c0(L)+16),
// c0(L) = 32*(L>>4) + (L&15)

// ---------------- prep: Wt, fc1t (K-permuted), BN scale/cc ----------------
__global__ __launch_bounds__(256) void k_prep(const float* __restrict__ W,
                                              const float* __restrict__ fc1,
                                              const float* __restrict__ fc1_b,
                                              const float* __restrict__ gamma,
                                              const float* __restrict__ beta,
                                              const float* __restrict__ mean,
                                              const float* __restrict__ var,
                                              unsigned short* __restrict__ Wt,
                                              unsigned short* __restrict__ fc1t,
                                              float* __restrict__ scale,
                                              float* __restrict__ cc) {
    int id = blockIdx.x * 256 + threadIdx.x;
    if (id < 32768) {                       // Wt[n][k] = bf16(W[k][n])
        int n = id >> 8, k = id & 255;
        Wt[id] = f2bf(W[k * HC + n]);
    }
    int id2 = id - 32768;                   // fc1t[j][q], q in h2 storage order
    if (id2 >= 0 && id2 < 16384) {
        int j = id2 >> 7, q = id2 & 127;
        int L = q >> 1, b = q & 1;
        int kch = 32 * (L >> 4) + (L & 15) + 16 * b;
        float v = (j < 64) ? fc1[kch * 64 + j] : fc1[(128 + kch) * 64 + (j - 64)];
        fc1t[id2] = f2bf(v);
    }
    int id3 = id - (32768 + 16384);
    if (id3 >= 0 && id3 < 128) {
        int jj = id3 & 63;
        float s = gamma[jj] * rsqrtf(var[jj] + 1e-5f);
        scale[id3] = s;
        cc[id3] = (id3 < 64) ? 0.f : (fc1_b[jj] - mean[jj]) * s + beta[jj];
    }
}

// ---------------- CSR build ----------------
__global__ void k_hist(const int* __restrict__ dst, int* __restrict__ deg) {
    int e = blockIdx.x * 256 + threadIdx.x;
    atomicAdd(&deg[dst[e]], 1);
}

__global__ void k_scan_part(const int* __restrict__ deg, int* __restrict__ part) {
    __shared__ int sd[256];
    int i = blockIdx.x * 256 + threadIdx.x;
    sd[threadIdx.x] = (i < N_NODES) ? deg[i] : 0;
    __syncthreads();
    for (int off = 128; off > 0; off >>= 1) {
        if (threadIdx.x < off) sd[threadIdx.x] += sd[threadIdx.x + off];
        __syncthreads();
    }
    if (threadIdx.x == 0) part[blockIdx.x] = sd[0];
}

__global__ void k_scan_mid(int* __restrict__ part, int* __restrict__ offs, int nb) {
    __shared__ int sd[256];
    int t = threadIdx.x;
    int v = (t < nb) ? part[t] : 0;
    sd[t] = v;
    __syncthreads();
    for (int off = 1; off < 256; off <<= 1) {
        int u = (t >= off) ? sd[t - off] : 0;
        __syncthreads();
        sd[t] += u;
        __syncthreads();
    }
    if (t < nb) part[t] = sd[t] - v;
    if (t == 255) offs[N_NODES] = sd[255];
}

__global__ void k_scan_final(const int* __restrict__ deg, const int* __restrict__ part,
                             int* __restrict__ offs, int* __restrict__ cur) {
    __shared__ int sd[256];
    int t = threadIdx.x;
    int i = blockIdx.x * 256 + t;
    int v = (i < N_NODES) ? deg[i] : 0;
    sd[t] = v;
    __syncthreads();
    for (int off = 1; off < 256; off <<= 1) {
        int u = (t >= off) ? sd[t - off] : 0;
        __syncthreads();
        sd[t] += u;
        __syncthreads();
    }
    if (i < N_NODES) {
        int o = part[blockIdx.x] + sd[t] - v;
        offs[i] = o;
        cur[i]  = o;
    }
}

__global__ void k_scatter(const int* __restrict__ src, const int* __restrict__ dst,
                          int* __restrict__ cur, int* __restrict__ csr_src) {
    int e = blockIdx.x * 256 + threadIdx.x;
    int d = dst[e];
    int pos = atomicAdd(&cur[d], 1);
    csr_src[pos] = src[e];
}

// ---------------- MFMA GEMM1: h = (x_hi+x_lo) @ Wt^T, fused att logits ----------------
__global__ __launch_bounds__(256) void k_mfma_xw(const float* __restrict__ x,
                                                 const unsigned short* __restrict__ Wt,
                                                 const float* __restrict__ att_src,
                                                 const float* __restrict__ att_dst,
                                                 unsigned* __restrict__ h_p,
                                                 float* __restrict__ as_,
                                                 float* __restrict__ ad_) {
    const int w = blockIdx.x * 4 + (threadIdx.x >> 6);
    if (w >= N_NODES / 16) return;
    const int lane = threadIdx.x & 63;
    const int c16  = lane & 15;
    const int kg   = lane >> 4;                 // 0..3
    const int r0   = w * 16;
    const float* xrow = x + (size_t)(r0 + c16) * F_IN + kg * 8;
    f32x4 acc[8] = {};
    for (int kk = 0; kk < 8; ++kk) {
        float4 f0 = *(const float4*)(xrow + kk * 32);
        float4 f1 = *(const float4*)(xrow + kk * 32 + 4);
        float fv[8] = {f0.x, f0.y, f0.z, f0.w, f1.x, f1.y, f1.z, f1.w};
        bf16x8 ahi, alo;
#pragma unroll
        for (int j = 0; j < 8; ++j) {
            unsigned u = __float_as_uint(fv[j]);
            float hval = __uint_as_float(u & 0xffff0000u);
            float d = fv[j] - hval;             // exact
            ahi[j] = (short)(u >> 16);
            alo[j] = (short)(__float_as_uint(d) >> 16);
        }
        const unsigned short* wp = Wt + c16 * 256 + kk * 32 + kg * 8;
#pragma unroll
        for (int cf = 0; cf < 8; ++cf) {
            bf16x8 b = *(const bf16x8*)(wp + cf * 16 * 256);
            acc[cf] = __builtin_amdgcn_mfma_f32_16x16x32_bf16(alo, b, acc[cf], 0, 0, 0);
            acc[cf] = __builtin_amdgcn_mfma_f32_16x16x32_bf16(ahi, b, acc[cf], 0, 0, 0);
        }
    }
    // fused attention logits: row r = r0 + kg*4 + i, col = cf*16 + c16
    float asv[8], adv[8];
#pragma unroll
    for (int q = 0; q < 8; ++q) { asv[q] = 0.f; adv[q] = 0.f; }
#pragma unroll
    for (int cf = 0; cf < 8; ++cf) {
        float wsv = att_src[cf * 16 + c16];
        float wdv = att_dst[cf * 16 + c16];
        int hb = (cf >> 2) * 4;
#pragma unroll
        for (int i = 0; i < 4; ++i) {
            asv[hb + i] += acc[cf][i] * wsv;
            adv[hb + i] += acc[cf][i] * wdv;
        }
    }
#pragma unroll
    for (int m = 1; m < 16; m <<= 1) {
#pragma unroll
        for (int q = 0; q < 8; ++q) {
            asv[q] += __shfl_xor(asv[q], m, 64);
            adv[q] += __shfl_xor(adv[q], m, 64);
        }
    }
    if (c16 == 0) {
#pragma unroll
        for (int i = 0; i < 4; ++i) {
            int row = r0 + kg * 4 + i;
            as_[row * 2]     = asv[i];
            as_[row * 2 + 1] = asv[4 + i];
            ad_[row * 2]     = adv[i];
            ad_[row * 2 + 1] = adv[4 + i];
        }
    }
    // store packed h: word (cf/2)*16 + c16 holds channels (cf*16+c16, (cf+1)*16+c16)
#pragma unroll
    for (int cf = 0; cf < 8; cf += 2) {
#pragma unroll
        for (int i = 0; i < 4; ++i) {
            int row = r0 + kg * 4 + i;
            unsigned pu = (unsigned)f2bf(acc[cf][i]) | ((unsigned)f2bf(acc[cf + 1][i]) << 16);
            h_p[(size_t)row * 64 + (cf >> 1) * 16 + c16] = pu;
        }
    }
}

// ---------------- k_agg: wave-per-node softmax + aggregate (packed bf16) ----------------
__global__ __launch_bounds__(256) void k_agg(const unsigned* __restrict__ h_p,
                                             const float* __restrict__ as_,
                                             const float* __restrict__ ad_,
                                             const int* __restrict__ offs,
                                             const int* __restrict__ csr_src,
                                             const float* __restrict__ conv_bias,
                                             unsigned* __restrict__ h2_p) {
    const int n    = blockIdx.x * 4 + (threadIdx.x >> 6);
    const int lane = threadIdx.x & 63;
    const int c0   = 32 * (lane >> 4) + (lane & 15);   // channels (c0, c0+16)
    const int hd   = lane >> 5;                        // head of both channels
    const float adn = ad_[n * 2 + hd];
    float acc0 = 0.f, acc1 = 0.f, accw = 0.f;
    const int beg = offs[n], end = offs[n + 1];
    int i = beg;
    for (; i + 1 < end; i += 2) {
        int s0 = csr_src[i], s1 = csr_src[i + 1];
        float e0 = as_[s0 * 2 + hd] + adn;
        float e1 = as_[s1 * 2 + hd] + adn;
        unsigned u0 = h_p[(size_t)s0 * 64 + lane];
        unsigned u1 = h_p[(size_t)s1 * 64 + lane];
        e0 = fmaxf(e0, 0.2f * e0);
        e1 = fmaxf(e1, 0.2f * e1);
        float w0 = __expf(e0), w1 = __expf(e1);
        float2 f0 = bf2(u0), f1 = bf2(u1);
        acc0 += w0 * f0.x + w1 * f1.x;
        acc1 += w0 * f0.y + w1 * f1.y;
        accw += w0 + w1;
    }
    if (i < end) {
        int s0 = csr_src[i];
        float e0 = as_[s0 * 2 + hd] + adn;
        unsigned u0 = h_p[(size_t)s0 * 64 + lane];
        e0 = fmaxf(e0, 0.2f * e0);
        float w0 = __expf(e0);
        float2 f0 = bf2(u0);
        acc0 += w0 * f0.x; acc1 += w0 * f0.y; accw += w0;
    }
    {   // self-loop
        float es = as_[n * 2 + hd] + adn;
        es = fmaxf(es, 0.2f * es);
        float wsl = __expf(es);
        float2 fn = bf2(h_p[(size_t)n * 64 + lane]);
        acc0 += wsl * fn.x; acc1 += wsl * fn.y; accw += wsl;
    }
    float b0 = conv_bias[c0], b1 = conv_bias[c0 + 16];
    float o0 = acc0 / accw + b0;
    float o1 = acc1 / accw + b1;
    o0 = fmaxf(o0, 0.01f * o0);
    o1 = fmaxf(o1, 0.01f * o1);
    h2_p[(size_t)n * 64 + lane] = (unsigned)f2bf(o0) | ((unsigned)f2bf(o1) << 16);
}

// ---------------- MFMA GEMM2: ab = BN-folded h2 @ fc1t^T ----------------
__global__ __launch_bounds__(256) void k_mfma_uv(const unsigned short* __restrict__ h2,
                                                 const unsigned short* __restrict__ fc1t,
                                                 const float* __restrict__ scale,
                                                 const float* __restrict__ cc,
                                                 unsigned* __restrict__ ab_p) {
    const int w = blockIdx.x * 4 + (threadIdx.x >> 6);
    if (w >= N_NODES / 16) return;
    const int lane = threadIdx.x & 63;
    const int c16  = lane & 15;
    const int kg   = lane >> 4;
    const int r0   = w * 16;
    const unsigned short* arow = h2 + (size_t)(r0 + c16) * HC + kg * 8;
    f32x4 acc[8] = {};
    for (int kk = 0; kk < 4; ++kk) {
        bf16x8 a = *(const bf16x8*)(arow + kk * 32);
        const unsigned short* wp = fc1t + c16 * HC + kk * 32 + kg * 8;
#pragma unroll
        for (int cf = 0; cf < 8; ++cf) {
            bf16x8 b = *(const bf16x8*)(wp + cf * 16 * HC);
            acc[cf] = __builtin_amdgcn_mfma_f32_16x16x32_bf16(a, b, acc[cf], 0, 0, 0);
        }
    }
#pragma unroll
    for (int cf = 0; cf < 8; cf += 2) {
        int j0 = cf * 16 + c16, j1 = j0 + 16;
        float s0 = scale[j0], s1 = scale[j1];
        float q0 = cc[j0],    q1 = cc[j1];
#pragma unroll
        for (int i = 0; i < 4; ++i) {
            int row = r0 + kg * 4 + i;
            unsigned pu = (unsigned)f2bf(acc[cf][i] * s0 + q0)
                        | ((unsigned)f2bf(acc[cf + 1][i] * s1 + q1) << 16);
            ab_p[(size_t)row * 64 + (cf >> 1) * 16 + c16] = pu;
        }
    }
}

// ---------------- k_edge: per-edge tail, 16 lanes/edge, packed channels ----------------
__global__ __launch_bounds__(256) void k_edge(const int* __restrict__ src,
                                              const int* __restrict__ dst,
                                              const unsigned* __restrict__ ab_p,
                                              const float* __restrict__ fc2_w,
                                              const float* __restrict__ fc2_b,
                                              float* __restrict__ out) {
    const int t = threadIdx.x;
    const int g = t >> 4;
    const int k = t & 15;
    // words L0=2k, L1=2k+1 of the A half; channels: c=32*(L>>4)+(L&15), c+16
    const int L0 = 2 * k, L1 = 2 * k + 1;
    const int ch[4] = {32 * (L0 >> 4) + (L0 & 15),
                       32 * (L0 >> 4) + (L0 & 15) + 16,
                       32 * (L1 >> 4) + (L1 & 15),
                       32 * (L1 >> 4) + (L1 & 15) + 16};
    float wr0[4], wr1[4], wr2[4];
#pragma unroll
    for (int q = 0; q < 4; ++q) {
        wr0[q] = fc2_w[ch[q] * 3 + 0];
        wr1[q] = fc2_w[ch[q] * 3 + 1];
        wr2[q] = fc2_w[ch[q] * 3 + 2];
    }
    const float ob0 = fc2_b[0], ob1 = fc2_b[1], ob2 = fc2_b[2];
    const int ebase = blockIdx.x * 256;
#pragma unroll 1
    for (int it = 0; it < 16; ++it) {
        const int e = ebase + it * 16 + g;
        const int s = src[e], d = dst[e];
        uint2 ua = *(const uint2*)(ab_p + (size_t)s * 64 + 2 * k);
        uint2 ub = *(const uint2*)(ab_p + (size_t)d * 64 + 32 + 2 * k);
        float2 a0 = bf2(ua.x), a1 = bf2(ua.y);
        float2 b0 = bf2(ub.x), b1 = bf2(ub.y);
        float z0 = a0.x + b0.x, z1 = a0.y + b0.y, z2 = a1.x + b1.x, z3 = a1.y + b1.y;
        z0 = fmaxf(z0, 0.01f * z0);
        z1 = fmaxf(z1, 0.01f * z1);
        z2 = fmaxf(z2, 0.01f * z2);
        z3 = fmaxf(z3, 0.01f * z3);
        float p0 = z0 * wr0[0] + z1 * wr0[1] + z2 * wr0[2] + z3 * wr0[3];
        float p1 = z0 * wr1[0] + z1 * wr1[1] + z2 * wr1[2] + z3 * wr1[3];
        float p2 = z0 * wr2[0] + z1 * wr2[1] + z2 * wr2[2] + z3 * wr2[3];
#pragma unroll
        for (int m = 1; m < 16; m <<= 1) {
            p0 += __shfl_xor(p0, m, 64);
            p1 += __shfl_xor(p1, m, 64);
            p2 += __shfl_xor(p2, m, 64);
        }
        if (k == 0) {
            float* o = out + (size_t)e * 3;
            o[0] = p0 + ob0;
            o[1] = p1 + ob1;
            o[2] = p2 + ob2;
        }
    }
}

extern "C" void kernel_launch(void* const* d_in, const int* in_sizes, int n_in,
                              void* d_out, int out_size, void* d_ws, size_t ws_size,
                              hipStream_t stream) {
    const float* x        = (const float*)d_in[0];
    const int*   ei       = (const int*)d_in[1];
    const float* W        = (const float*)d_in[2];
    const float* att_src  = (const float*)d_in[3];
    const float* att_dst  = (const float*)d_in[4];
    const float* conv_b   = (const float*)d_in[5];
    const float* fc1_w    = (const float*)d_in[6];
    const float* fc1_b    = (const float*)d_in[7];
    const float* gamma    = (const float*)d_in[8];
    const float* beta     = (const float*)d_in[9];
    const float* mean     = (const float*)d_in[10];
    const float* var      = (const float*)d_in[11];
    const float* fc2_w    = (const float*)d_in[12];
    const float* fc2_b    = (const float*)d_in[13];
    float*       out      = (float*)d_out;
    char*        ws       = (char*)d_ws;

    const int* src = ei;
    const int* dst = ei + N_EDGES;

    unsigned*       h_p   = (unsigned*)(ws + OFF_HBF);
    unsigned*       h2_p  = (unsigned*)(ws + OFF_H2);
    unsigned*       ab_p  = (unsigned*)(ws + OFF_AB);
    float*          as_   = (float*)(ws + OFF_AS);
    float*          ad_   = (float*)(ws + OFF_AD);
    int*            offs  = (int*)(ws + OFF_OFFS);
    int*            deg   = (int*)(ws + OFF_DEG);
    int*            cur   = (int*)(ws + OFF_CUR);
    int*            part  = (int*)(ws + OFF_PART);
    int*            csr   = (int*)(ws + OFF_CSR);
    unsigned short* Wt    = (unsigned short*)(ws + OFF_WT);
    unsigned short* fc1t  = (unsigned short*)(ws + OFF_FC1T);
    float*          scale = (float*)(ws + OFF_SCALE);
    float*          cc    = (float*)(ws + OFF_CC);

    // prep (tiny)
    k_prep<<<193, 256, 0, stream>>>(W, fc1_w, fc1_b, gamma, beta, mean, var,
                                    Wt, fc1t, scale, cc);

    // CSR build
    hipMemsetAsync(deg, 0, N_NODES * sizeof(int), stream);
    k_hist      <<<N_EDGES / 256, 256, 0, stream>>>(dst, deg);
    k_scan_part <<<(N_NODES + 255) / 256, 256, 0, stream>>>(deg, part);
    k_scan_mid  <<<1, 256, 0, stream>>>(part, offs, (N_NODES + 255) / 256);
    k_scan_final<<<(N_NODES + 255) / 256, 256, 0, stream>>>(deg, part, offs, cur);
    k_scatter   <<<N_EDGES / 256, 256, 0, stream>>>(src, dst, cur, csr);

    // node pipeline
    const int gemm_blocks = (N_NODES / 16 + 3) / 4;   // 782
    k_mfma_xw<<<gemm_blocks, 256, 0, stream>>>(x, Wt, att_src, att_dst, h_p, as_, ad_);
    k_agg    <<<N_NODES / 4, 256, 0, stream>>>(h_p, as_, ad_, offs, csr, conv_b, h2_p);
    k_mfma_uv<<<gemm_blocks, 256, 0, stream>>>((const unsigned short*)h2_p, fc1t, scale, cc, ab_p);

    // edge tail
    k_edge<<<N_EDGES / 256, 256, 0, stream>>>(src, dst, ab_p, fc2_w, fc2_b, out);
}

// Round 4
// 236.761 us; speedup vs baseline: 2.0314x; 1.0640x over previous
//
#include <hip/hip_runtime.h>

#define N_NODES 50000
#define N_EDGES 800000
#define F_IN    256
#define C_DIM   64
#define HC      128   // H*C

typedef __attribute__((ext_vector_type(8))) short bf16x8;
typedef __attribute__((ext_vector_type(4))) float f32x4;

// ---------------- workspace layout (bytes) ----------------
static constexpr size_t OFF_HBF   = 0;           // u32  h packed  [N][64] = 12.8 MB
static constexpr size_t OFF_H2    = 12800000;    // u32  h2 packed [N][64] = 12.8 MB
static constexpr size_t OFF_AB    = 25600000;    // u32  ab packed [N][64] = 12.8 MB
static constexpr size_t OFF_AS    = 38400000;    // f32 [N][2]
static constexpr size_t OFF_AD    = 38800000;
static constexpr size_t OFF_OFFS  = 39200000;    // i32 N+1
static constexpr size_t OFF_DEG   = 39400064;
static constexpr size_t OFF_CUR   = 39600064;
static constexpr size_t OFF_PART  = 39800064;
static constexpr size_t OFF_CSR2  = 39801088;    // int2 [E] (src, eid) = 6.4 MB
static constexpr size_t OFF_WTAB  = 46201088;    // float2 [E] (w_h0, w_h1) = 6.4 MB
static constexpr size_t OFF_WT    = 52601088;    // bf16 Wt   [128][256] = 64 KB
static constexpr size_t OFF_FC1T  = 52666624;    // bf16 fc1t [128][128] = 32 KB
static constexpr size_t OFF_SCALE = 52699392;    // f32 [128]
static constexpr size_t OFF_CC    = 52699904;    // f32 [128]

__device__ __forceinline__ float2 bf2(unsigned u) {
    float2 r;
    r.x = __uint_as_float(u << 16);
    r.y = __uint_as_float(u & 0xffff0000u);
    return r;
}
__device__ __forceinline__ unsigned short f2bf(float f) {
    unsigned u = __float_as_uint(f);
    return (unsigned short)((u + 0x7fffu + ((u >> 16) & 1u)) >> 16);  // RNE
}
// packed-channel mapping: word q (0..63) of a row holds channels (c0(q), c0(q)+16),
// c0(q) = 32*(q>>4) + (q&15).  words 0..31 <-> channels 0..63, words 32..63 <-> 64..127

// ---------------- prep: Wt, fc1t (K-permuted), BN scale/cc ----------------
__global__ __launch_bounds__(256) void k_prep(const float* __restrict__ W,
                                              const float* __restrict__ fc1,
                                              const float* __restrict__ fc1_b,
                                              const float* __restrict__ gamma,
                                              const float* __restrict__ beta,
                                              const float* __restrict__ mean,
                                              const float* __restrict__ var,
                                              unsigned short* __restrict__ Wt,
                                              unsigned short* __restrict__ fc1t,
                                              float* __restrict__ scale,
                                              float* __restrict__ cc) {
    int id = blockIdx.x * 256 + threadIdx.x;
    if (id < 32768) {                       // Wt[n][k] = bf16(W[k][n])
        int n = id >> 8, k = id & 255;
        Wt[id] = f2bf(W[k * HC + n]);
    }
    int id2 = id - 32768;                   // fc1t[j][q], q in h2 storage order
    if (id2 >= 0 && id2 < 16384) {
        int j = id2 >> 7, q = id2 & 127;
        int L = q >> 1, b = q & 1;
        int kch = 32 * (L >> 4) + (L & 15) + 16 * b;
        float v = (j < 64) ? fc1[kch * 64 + j] : fc1[(128 + kch) * 64 + (j - 64)];
        fc1t[id2] = f2bf(v);
    }
    int id3 = id - (32768 + 16384);
    if (id3 >= 0 && id3 < 128) {
        int jj = id3 & 63;
        float s = gamma[jj] * rsqrtf(var[jj] + 1e-5f);
        scale[id3] = s;
        cc[id3] = (id3 < 64) ? 0.f : (fc1_b[jj] - mean[jj]) * s + beta[jj];
    }
}

// ---------------- CSR build ----------------
__global__ void k_hist(const int* __restrict__ dst, int* __restrict__ deg) {
    int e = blockIdx.x * 256 + threadIdx.x;
    atomicAdd(&deg[dst[e]], 1);
}

__global__ void k_scan_part(const int* __restrict__ deg, int* __restrict__ part) {
    __shared__ int sd[256];
    int i = blockIdx.x * 256 + threadIdx.x;
    sd[threadIdx.x] = (i < N_NODES) ? deg[i] : 0;
    __syncthreads();
    for (int off = 128; off > 0; off >>= 1) {
        if (threadIdx.x < off) sd[threadIdx.x] += sd[threadIdx.x + off];
        __syncthreads();
    }
    if (threadIdx.x == 0) part[blockIdx.x] = sd[0];
}

__global__ void k_scan_mid(int* __restrict__ part, int* __restrict__ offs, int nb) {
    __shared__ int sd[256];
    int t = threadIdx.x;
    int v = (t < nb) ? part[t] : 0;
    sd[t] = v;
    __syncthreads();
    for (int off = 1; off < 256; off <<= 1) {
        int u = (t >= off) ? sd[t - off] : 0;
        __syncthreads();
        sd[t] += u;
        __syncthreads();
    }
    if (t < nb) part[t] = sd[t] - v;
    if (t == 255) offs[N_NODES] = sd[255];
}

__global__ void k_scan_final(const int* __restrict__ deg, const int* __restrict__ part,
                             int* __restrict__ offs, int* __restrict__ cur) {
    __shared__ int sd[256];
    int t = threadIdx.x;
    int i = blockIdx.x * 256 + t;
    int v = (i < N_NODES) ? deg[i] : 0;
    sd[t] = v;
    __syncthreads();
    for (int off = 1; off < 256; off <<= 1) {
        int u = (t >= off) ? sd[t - off] : 0;
        __syncthreads();
        sd[t] += u;
        __syncthreads();
    }
    if (i < N_NODES) {
        int o = part[blockIdx.x] + sd[t] - v;
        offs[i] = o;
        cur[i]  = o;
    }
}

// scatter + fused softmax-weight computation
__global__ void k_scatter_w(const int* __restrict__ src, const int* __restrict__ dst,
                            const float* __restrict__ as_, const float* __restrict__ ad_,
                            int* __restrict__ cur, int2* __restrict__ csr2,
                            float2* __restrict__ wtab) {
    int e = blockIdx.x * 256 + threadIdx.x;
    int s = src[e], d = dst[e];
    int pos = atomicAdd(&cur[d], 1);
    float2 asv = ((const float2*)as_)[s];
    float2 adv = ((const float2*)ad_)[d];
    float e0 = asv.x + adv.x;
    float e1 = asv.y + adv.y;
    e0 = fmaxf(e0, 0.2f * e0);
    e1 = fmaxf(e1, 0.2f * e1);
    csr2[pos] = make_int2(s, e);
    wtab[pos] = make_float2(__expf(e0), __expf(e1));
}

// ---------------- MFMA GEMM1: h = (x_hi+x_lo) @ Wt^T, fused att logits ----------------
__global__ __launch_bounds__(256) void k_mfma_xw(const float* __restrict__ x,
                                                 const unsigned short* __restrict__ Wt,
                                                 const float* __restrict__ att_src,
                                                 const float* __restrict__ att_dst,
                                                 unsigned* __restrict__ h_p,
                                                 float* __restrict__ as_,
                                                 float* __restrict__ ad_) {
    const int w = blockIdx.x * 4 + (threadIdx.x >> 6);
    if (w >= N_NODES / 16) return;
    const int lane = threadIdx.x & 63;
    const int c16  = lane & 15;
    const int kg   = lane >> 4;                 // 0..3
    const int r0   = w * 16;
    const float* xrow = x + (size_t)(r0 + c16) * F_IN + kg * 8;
    f32x4 acc[8] = {};
    for (int kk = 0; kk < 8; ++kk) {
        float4 f0 = *(const float4*)(xrow + kk * 32);
        float4 f1 = *(const float4*)(xrow + kk * 32 + 4);
        float fv[8] = {f0.x, f0.y, f0.z, f0.w, f1.x, f1.y, f1.z, f1.w};
        bf16x8 ahi, alo;
#pragma unroll
        for (int j = 0; j < 8; ++j) {
            unsigned u = __float_as_uint(fv[j]);
            float hval = __uint_as_float(u & 0xffff0000u);
            float d = fv[j] - hval;             // exact
            ahi[j] = (short)(u >> 16);
            alo[j] = (short)(__float_as_uint(d) >> 16);
        }
        const unsigned short* wp = Wt + c16 * 256 + kk * 32 + kg * 8;
#pragma unroll
        for (int cf = 0; cf < 8; ++cf) {
            bf16x8 b = *(const bf16x8*)(wp + cf * 16 * 256);
            acc[cf] = __builtin_amdgcn_mfma_f32_16x16x32_bf16(alo, b, acc[cf], 0, 0, 0);
            acc[cf] = __builtin_amdgcn_mfma_f32_16x16x32_bf16(ahi, b, acc[cf], 0, 0, 0);
        }
    }
    // fused attention logits: row r = r0 + kg*4 + i, col = cf*16 + c16
    float asv[8], adv[8];
#pragma unroll
    for (int q = 0; q < 8; ++q) { asv[q] = 0.f; adv[q] = 0.f; }
#pragma unroll
    for (int cf = 0; cf < 8; ++cf) {
        float wsv = att_src[cf * 16 + c16];
        float wdv = att_dst[cf * 16 + c16];
        int hb = (cf >> 2) * 4;
#pragma unroll
        for (int i = 0; i < 4; ++i) {
            asv[hb + i] += acc[cf][i] * wsv;
            adv[hb + i] += acc[cf][i] * wdv;
        }
    }
#pragma unroll
    for (int m = 1; m < 16; m <<= 1) {
#pragma unroll
        for (int q = 0; q < 8; ++q) {
            asv[q] += __shfl_xor(asv[q], m, 64);
            adv[q] += __shfl_xor(adv[q], m, 64);
        }
    }
    if (c16 == 0) {
#pragma unroll
        for (int i = 0; i < 4; ++i) {
            int row = r0 + kg * 4 + i;
            as_[row * 2]     = asv[i];
            as_[row * 2 + 1] = asv[4 + i];
            ad_[row * 2]     = adv[i];
            ad_[row * 2 + 1] = adv[4 + i];
        }
    }
#pragma unroll
    for (int cf = 0; cf < 8; cf += 2) {
#pragma unroll
        for (int i = 0; i < 4; ++i) {
            int row = r0 + kg * 4 + i;
            unsigned pu = (unsigned)f2bf(acc[cf][i]) | ((unsigned)f2bf(acc[cf + 1][i]) << 16);
            h_p[(size_t)row * 64 + (cf >> 1) * 16 + c16] = pu;
        }
    }
}

// ---------------- k_agg: half-wave dual-edge weighted gather ----------------
__global__ __launch_bounds__(256) void k_agg(const unsigned* __restrict__ h_p,
                                             const float* __restrict__ as_,
                                             const float* __restrict__ ad_,
                                             const int* __restrict__ offs,
                                             const int2* __restrict__ csr2,
                                             const float2* __restrict__ wtab,
                                             const float* __restrict__ conv_bias,
                                             unsigned* __restrict__ h2_p) {
    const int n    = blockIdx.x * 4 + (threadIdx.x >> 6);
    const int lane = threadIdx.x & 63;
    const int L    = lane & 31;          // word-pair index within row
    const int half = lane >> 5;          // which edge of the pair
    const int hd   = L >> 4;             // head of this lane's 4 channels
    const uint2* hrows = (const uint2*)h_p;
    float a0 = 0.f, a1 = 0.f, a2 = 0.f, a3 = 0.f, accw = 0.f;
    const int beg = offs[n], end = offs[n + 1];
    int i = beg + half;
    for (; i + 2 < end; i += 4) {        // 4 edges per wave-iteration, 2 gathers in flight
        int2  c0 = csr2[i];
        int2  c1 = csr2[i + 2];
        float2 wv0 = wtab[i];
        float2 wv1 = wtab[i + 2];
        uint2 u0 = hrows[(unsigned)(c0.x * 32 + L)];
        uint2 u1 = hrows[(unsigned)(c1.x * 32 + L)];
        float w0 = hd ? wv0.y : wv0.x;
        float w1 = hd ? wv1.y : wv1.x;
        float2 f0a = bf2(u0.x), f0b = bf2(u0.y);
        float2 f1a = bf2(u1.x), f1b = bf2(u1.y);
        a0 += w0 * f0a.x + w1 * f1a.x;
        a1 += w0 * f0a.y + w1 * f1a.y;
        a2 += w0 * f0b.x + w1 * f1b.x;
        a3 += w0 * f0b.y + w1 * f1b.y;
        accw += w0 + w1;
    }
    for (; i < end; i += 2) {
        int2  c0 = csr2[i];
        float2 wv0 = wtab[i];
        uint2 u0 = hrows[(unsigned)(c0.x * 32 + L)];
        float w0 = hd ? wv0.y : wv0.x;
        float2 f0a = bf2(u0.x), f0b = bf2(u0.y);
        a0 += w0 * f0a.x;
        a1 += w0 * f0a.y;
        a2 += w0 * f0b.x;
        a3 += w0 * f0b.y;
        accw += w0;
    }
    a0 += __shfl_xor(a0, 32, 64);
    a1 += __shfl_xor(a1, 32, 64);
    a2 += __shfl_xor(a2, 32, 64);
    a3 += __shfl_xor(a3, 32, 64);
    accw += __shfl_xor(accw, 32, 64);
    if (half == 0) {
        // self-loop
        float es = as_[n * 2 + hd] + ad_[n * 2 + hd];
        es = fmaxf(es, 0.2f * es);
        float wsl = __expf(es);
        uint2 un = hrows[(unsigned)(n * 32 + L)];
        float2 na = bf2(un.x), nb = bf2(un.y);
        a0 += wsl * na.x; a1 += wsl * na.y; a2 += wsl * nb.x; a3 += wsl * nb.y;
        accw += wsl;
        const int q0 = 2 * L, q1 = 2 * L + 1;
        const int c00 = 32 * (q0 >> 4) + (q0 & 15);
        const int c01 = 32 * (q1 >> 4) + (q1 & 15);
        float rinv = 1.f / accw;
        float o0 = a0 * rinv + conv_bias[c00];
        float o1 = a1 * rinv + conv_bias[c00 + 16];
        float o2 = a2 * rinv + conv_bias[c01];
        float o3 = a3 * rinv + conv_bias[c01 + 16];
        o0 = fmaxf(o0, 0.01f * o0);
        o1 = fmaxf(o1, 0.01f * o1);
        o2 = fmaxf(o2, 0.01f * o2);
        o3 = fmaxf(o3, 0.01f * o3);
        unsigned p0 = (unsigned)f2bf(o0) | ((unsigned)f2bf(o1) << 16);
        unsigned p1 = (unsigned)f2bf(o2) | ((unsigned)f2bf(o3) << 16);
        ((uint2*)h2_p)[(unsigned)(n * 32 + L)] = make_uint2(p0, p1);
    }
}

// ---------------- MFMA GEMM2: ab = BN-folded h2 @ fc1t^T ----------------
__global__ __launch_bounds__(256) void k_mfma_uv(const unsigned short* __restrict__ h2,
                                                 const unsigned short* __restrict__ fc1t,
                                                 const float* __restrict__ scale,
                                                 const float* __restrict__ cc,
                                                 unsigned* __restrict__ ab_p) {
    const int w = blockIdx.x * 4 + (threadIdx.x >> 6);
    if (w >= N_NODES / 16) return;
    const int lane = threadIdx.x & 63;
    const int c16  = lane & 15;
    const int kg   = lane >> 4;
    const int r0   = w * 16;
    const unsigned short* arow = h2 + (size_t)(r0 + c16) * HC + kg * 8;
    f32x4 acc[8] = {};
    for (int kk = 0; kk < 4; ++kk) {
        bf16x8 a = *(const bf16x8*)(arow + kk * 32);
        const unsigned short* wp = fc1t + c16 * HC + kk * 32 + kg * 8;
#pragma unroll
        for (int cf = 0; cf < 8; ++cf) {
            bf16x8 b = *(const bf16x8*)(wp + cf * 16 * HC);
            acc[cf] = __builtin_amdgcn_mfma_f32_16x16x32_bf16(a, b, acc[cf], 0, 0, 0);
        }
    }
#pragma unroll
    for (int cf = 0; cf < 8; cf += 2) {
        int j0 = cf * 16 + c16, j1 = j0 + 16;
        float s0 = scale[j0], s1 = scale[j1];
        float q0 = cc[j0],    q1 = cc[j1];
#pragma unroll
        for (int i = 0; i < 4; ++i) {
            int row = r0 + kg * 4 + i;
            unsigned pu = (unsigned)f2bf(acc[cf][i] * s0 + q0)
                        | ((unsigned)f2bf(acc[cf + 1][i] * s1 + q1) << 16);
            ab_p[(size_t)row * 64 + (cf >> 1) * 16 + c16] = pu;
        }
    }
}

// ---------------- k_edge: CSR-order tail, B-half hoisted, 8 lanes/edge ----------------
__global__ __launch_bounds__(256) void k_edge(const int* __restrict__ offs,
                                              const int2* __restrict__ csr2,
                                              const unsigned* __restrict__ ab_p,
                                              const float* __restrict__ fc2_w,
                                              const float* __restrict__ fc2_b,
                                              float* __restrict__ out) {
    const int n    = blockIdx.x * 4 + (threadIdx.x >> 6);
    const int lane = threadIdx.x & 63;
    const int g = lane >> 3;            // edge slot 0..7
    const int k = lane & 7;             // 16B chunk: words 4k..4k+3
    float wr[3][8];
#pragma unroll
    for (int j = 0; j < 4; ++j) {
        int q = 4 * k + j;
        int c = 32 * (q >> 4) + (q & 15);
#pragma unroll
        for (int r = 0; r < 3; ++r) {
            wr[r][2 * j]     = fc2_w[c * 3 + r];
            wr[r][2 * j + 1] = fc2_w[(c + 16) * 3 + r];
        }
    }
    const float ob0 = fc2_b[0], ob1 = fc2_b[1], ob2 = fc2_b[2];
    const uint4* abv = (const uint4*)ab_p;
    // B half of dst node n (reused for all its edges)
    uint4 ub = abv[(unsigned)(n * 16 + 8 + k)];
    float2 b0 = bf2(ub.x), b1 = bf2(ub.y), b2 = bf2(ub.z), b3 = bf2(ub.w);
    const int beg = offs[n], end = offs[n + 1];
    for (int base = beg; base < end; base += 8) {
        int idx = base + g;
        bool valid = idx < end;
        int2 ce = valid ? csr2[idx] : make_int2(0, 0);
        uint4 ua = abv[(unsigned)(ce.x * 16 + k)];
        float2 a0 = bf2(ua.x), a1 = bf2(ua.y), a2 = bf2(ua.z), a3 = bf2(ua.w);
        float z0 = a0.x + b0.x, z1 = a0.y + b0.y;
        float z2 = a1.x + b1.x, z3 = a1.y + b1.y;
        float z4 = a2.x + b2.x, z5 = a2.y + b2.y;
        float z6 = a3.x + b3.x, z7 = a3.y + b3.y;
        z0 = fmaxf(z0, 0.01f * z0); z1 = fmaxf(z1, 0.01f * z1);
        z2 = fmaxf(z2, 0.01f * z2); z3 = fmaxf(z3, 0.01f * z3);
        z4 = fmaxf(z4, 0.01f * z4); z5 = fmaxf(z5, 0.01f * z5);
        z6 = fmaxf(z6, 0.01f * z6); z7 = fmaxf(z7, 0.01f * z7);
        float p0 = z0*wr[0][0] + z1*wr[0][1] + z2*wr[0][2] + z3*wr[0][3]
                 + z4*wr[0][4] + z5*wr[0][5] + z6*wr[0][6] + z7*wr[0][7];
        float p1 = z0*wr[1][0] + z1*wr[1][1] + z2*wr[1][2] + z3*wr[1][3]
                 + z4*wr[1][4] + z5*wr[1][5] + z6*wr[1][6] + z7*wr[1][7];
        float p2 = z0*wr[2][0] + z1*wr[2][1] + z2*wr[2][2] + z3*wr[2][3]
                 + z4*wr[2][4] + z5*wr[2][5] + z6*wr[2][6] + z7*wr[2][7];
#pragma unroll
        for (int m = 1; m < 8; m <<= 1) {
            p0 += __shfl_xor(p0, m, 64);
            p1 += __shfl_xor(p1, m, 64);
            p2 += __shfl_xor(p2, m, 64);
        }
        if (k == 0 && valid) {
            float* o = out + (size_t)ce.y * 3;
            o[0] = p0 + ob0;
            o[1] = p1 + ob1;
            o[2] = p2 + ob2;
        }
    }
}

extern "C" void kernel_launch(void* const* d_in, const int* in_sizes, int n_in,
                              void* d_out, int out_size, void* d_ws, size_t ws_size,
                              hipStream_t stream) {
    const float* x        = (const float*)d_in[0];
    const int*   ei       = (const int*)d_in[1];
    const float* W        = (const float*)d_in[2];
    const float* att_src  = (const float*)d_in[3];
    const float* att_dst  = (const float*)d_in[4];
    const float* conv_b   = (const float*)d_in[5];
    const float* fc1_w    = (const float*)d_in[6];
    const float* fc1_b    = (const float*)d_in[7];
    const float* gamma    = (const float*)d_in[8];
    const float* beta     = (const float*)d_in[9];
    const float* mean     = (const float*)d_in[10];
    const float* var      = (const float*)d_in[11];
    const float* fc2_w    = (const float*)d_in[12];
    const float* fc2_b    = (const float*)d_in[13];
    float*       out      = (float*)d_out;
    char*        ws       = (char*)d_ws;

    const int* src = ei;
    const int* dst = ei + N_EDGES;

    unsigned*       h_p   = (unsigned*)(ws + OFF_HBF);
    unsigned*       h2_p  = (unsigned*)(ws + OFF_H2);
    unsigned*       ab_p  = (unsigned*)(ws + OFF_AB);
    float*          as_   = (float*)(ws + OFF_AS);
    float*          ad_   = (float*)(ws + OFF_AD);
    int*            offs  = (int*)(ws + OFF_OFFS);
    int*            deg   = (int*)(ws + OFF_DEG);
    int*            cur   = (int*)(ws + OFF_CUR);
    int*            part  = (int*)(ws + OFF_PART);
    int2*           csr2  = (int2*)(ws + OFF_CSR2);
    float2*         wtab  = (float2*)(ws + OFF_WTAB);
    unsigned short* Wt    = (unsigned short*)(ws + OFF_WT);
    unsigned short* fc1t  = (unsigned short*)(ws + OFF_FC1T);
    float*          scale = (float*)(ws + OFF_SCALE);
    float*          cc    = (float*)(ws + OFF_CC);

    // prep (tiny)
    k_prep<<<193, 256, 0, stream>>>(W, fc1_w, fc1_b, gamma, beta, mean, var,
                                    Wt, fc1t, scale, cc);

    // CSR build
    hipMemsetAsync(deg, 0, N_NODES * sizeof(int), stream);
    k_hist      <<<N_EDGES / 256, 256, 0, stream>>>(dst, deg);
    k_scan_part <<<(N_NODES + 255) / 256, 256, 0, stream>>>(deg, part);
    k_scan_mid  <<<1, 256, 0, stream>>>(part, offs, (N_NODES + 255) / 256);
    k_scan_final<<<(N_NODES + 255) / 256, 256, 0, stream>>>(deg, part, offs, cur);

    // node pipeline
    const int gemm_blocks = (N_NODES / 16 + 3) / 4;   // 782
    k_mfma_xw  <<<gemm_blocks, 256, 0, stream>>>(x, Wt, att_src, att_dst, h_p, as_, ad_);
    k_scatter_w<<<N_EDGES / 256, 256, 0, stream>>>(src, dst, as_, ad_, cur, csr2, wtab);
    k_agg      <<<N_NODES / 4, 256, 0, stream>>>(h_p, as_, ad_, offs, csr2, wtab, conv_b, h2_p);
    k_mfma_uv  <<<gemm_blocks, 256, 0, stream>>>((const unsigned short*)h2_p, fc1t, scale, cc, ab_p);

    // edge tail
    k_edge<<<N_NODES / 4, 256, 0, stream>>>(offs, csr2, ab_p, fc2_w, fc2_b, out);
}